// Round 3
// baseline (318.756 us; speedup 1.0000x reference)
//
#include <hip/hip_runtime.h>
#include <math.h>

// Problem constants (x: [32, 256, 56, 56] fp32)
#define B_    32
#define C_    256
#define H_    56
#define W_    56
#define HW_   (H_ * W_)        // 3136
#define BHW_  (B_ * HW_)       // 100352
#define HW4_  (HW_ / 4)        // 784 float4 per (b,c) plane
#define NF4_  (BHW_ / 4)       // 25088 global float4 positions
#define GRID_ 784              // 784 = 8 XCDs * 98 blocks
#define CHUNKF4_ 32            // 32 consecutive float4 per block (784*32=25088)
#define POSPB_   128           // 128 float positions per block
#define NXCD_ 8
#define F4PX_ (NF4_ / NXCD_)   // 3136 f4 per XCD slab = 4 whole images
                               // (slabs align to image boundaries -> conv
                               //  halos never cross XCD slabs)

typedef float f4v __attribute__((ext_vector_type(4)));

// ---------------------------------------------------------------------------
// Software grid barrier. Monotonic epoch counters in zero-initialized device
// globals: epoch = arrivals / GRID_, so NO reset is needed across hipGraph
// replays (cooperative launch is NOT graph-capturable in this harness — R2
// failed with an unlaunched kernel; this replaces it).
// Residency proof: __launch_bounds__(256,4) -> VGPR<=128, LDS 9.5KB<=40KB
// -> 4 blocks/CU resident -> capacity 1024 >= 784 grid. Spin is bounded so
// a wrong assumption fails fast instead of hanging the bench.
// ---------------------------------------------------------------------------
__device__ unsigned g_count;    // zero-init at module load, monotonic
__device__ unsigned g_release;  // epoch release counter

__device__ __forceinline__ void grid_barrier(int t) {
  __syncthreads();
  if (t == 0) {
    __threadfence();  // release: pool writes visible device-wide (cross-XCD)
    unsigned old = atomicAdd(&g_count, 1u);
    unsigned epoch = old / (unsigned)GRID_;
    if (old % (unsigned)GRID_ == (unsigned)(GRID_ - 1)) {
      atomicAdd(&g_release, 1u);           // g_release becomes epoch+1
    } else {
      unsigned spins = 0;
      while (__hip_atomic_load(&g_release, __ATOMIC_ACQUIRE,
                               __HIP_MEMORY_SCOPE_AGENT) <= epoch) {
        __builtin_amdgcn_s_sleep(16);
        if (++spins > 4000000u) break;     // bounded: fail fast, never hang
      }
    }
    __threadfence();  // acquire side
  }
  __syncthreads();
}

// ---------------------------------------------------------------------------
// Fused kernel: reduce -> grid barrier -> conv+sigmoid -> apply.
// 784 blocks x 256 threads.
// XCD-contiguous bijective remap (784 = 8*98): block b -> xcd = b%8,
// j = b/8; block covers f4 range [xcd*3136 + 32j, +32). Each XCD streams a
// contiguous 12.8 MB slab; slab = 4 whole images, so the conv's +/-3-row
// pool halo is produced within the same XCD (L2-local after the barrier).
//
// Phase 1 (reduce): lane = t&31 -> 512-B wave segments; cgrp = t>>5 -> 8
// groups x 32 channels; LDS combine -> pool[B,2,HW].
// Phase 2a (conv): 2 threads/position, 49-tap conv from pool (L2-resident),
// pair-sum via LDS, sigmoid -> 128 gates in LDS. Gate never touches HBM.
// Phase 2b (apply): out = x * gate, 32 channels/thread; x re-read is
// L3-resident from phase 1; NT stores keep out from evicting x.
// ---------------------------------------------------------------------------
__global__ __launch_bounds__(256, 4) void sa_fused_kernel(
    const float* __restrict__ x, const float* __restrict__ wt,
    float* __restrict__ out, float* __restrict__ pool) {
  const int t = threadIdx.x;
  const unsigned b = blockIdx.x;
  const unsigned xcd = b % NXCD_;            // XCD-contiguous remap
  const unsigned j = b / NXCD_;
  const unsigned if4base = xcd * F4PX_ + j * CHUNKF4_;

  const int lane = t & 31;
  const int cgrp = t >> 5;                   // 0..7 (32 channels each)
  const unsigned if4 = if4base + (unsigned)lane;
  const unsigned bimg = if4 / HW4_;          // per-lane: handles image straddle
  const unsigned hw4 = if4 % HW4_;
  const f4v* __restrict__ x4 = (const f4v*)x;
  f4v* __restrict__ o4 = (f4v*)out;
  const unsigned base = (bimg * C_ + (unsigned)cgrp * 32u) * HW4_ + hw4;

  // ---- Phase 1: channel mean+max over 32 channels/thread ----
  f4v s = {0.f, 0.f, 0.f, 0.f};
  f4v m = {-INFINITY, -INFINITY, -INFINITY, -INFINITY};
#pragma unroll 8
  for (int k = 0; k < 32; ++k) {             // c = cgrp*32 + k
    f4v v = x4[base + (unsigned)k * HW4_];
    s += v;
    m = (f4v){fmaxf(m.x, v.x), fmaxf(m.y, v.y),
              fmaxf(m.z, v.z), fmaxf(m.w, v.w)};
  }

  __shared__ f4v ssum[8][32];
  __shared__ f4v smax[8][32];
  ssum[cgrp][lane] = s;
  smax[cgrp][lane] = m;
  __syncthreads();

  if (t < 32) {
    f4v S = ssum[0][t];
    f4v M = smax[0][t];
#pragma unroll
    for (int g = 1; g < 8; ++g) {
      f4v sg = ssum[g][t];
      f4v mg = smax[g][t];
      S += sg;
      M = (f4v){fmaxf(M.x, mg.x), fmaxf(M.y, mg.y),
                fmaxf(M.z, mg.z), fmaxf(M.w, mg.w)};
    }
    f4v* p4 = (f4v*)pool;
    const unsigned jf4 = if4base + (unsigned)t;
    const unsigned bb = jf4 / HW4_;
    const unsigned hh = jf4 % HW4_;
    p4[bb * 2 * HW4_ + hh]        = S * (1.0f / (float)C_);  // avg plane
    p4[bb * 2 * HW4_ + HW4_ + hh] = M;                       // max plane
  }

  // ---- grid-wide software barrier ----
  grid_barrier(t);

  // ---- Phase 2a: 7x7 conv + sigmoid into LDS gate ----
  __shared__ float partial[256];
  __shared__ f4v sgate4[CHUNKF4_];           // 128 gate floats
  {
    const int pos = t >> 1;                  // 0..127
    const int ic = t & 1;
    const unsigned p = if4base * 4u + (unsigned)pos;
    const unsigned bimg_a = p / HW_;
    const unsigned hw = p % HW_;
    const int h = (int)(hw / W_);
    const int w = (int)(hw % W_);
    const float* pl = pool + ((long)bimg_a * 2 + ic) * HW_;
    const float* wr0 = wt + ic * 49;
    float acc = 0.f;
#pragma unroll
    for (int kh = 0; kh < 7; ++kh) {
      const int ih = h + kh - 3;
      if (ih < 0 || ih >= H_) continue;
      const float* row = pl + ih * W_;
      const float* wr = wr0 + kh * 7;
#pragma unroll
      for (int kw = 0; kw < 7; ++kw) {
        const int iw = w + kw - 3;
        if (iw < 0 || iw >= W_) continue;
        acc = fmaf(row[iw], wr[kw], acc);
      }
    }
    partial[t] = acc;
  }
  __syncthreads();
  if (t < POSPB_) {
    float a = partial[2 * t] + partial[2 * t + 1];
    ((float*)sgate4)[t] = 1.0f / (1.0f + __expf(-a));
  }
  __syncthreads();

  // ---- Phase 2b: out = x * gate over 32 channels/thread ----
  const f4v g = sgate4[lane];
#pragma unroll 8
  for (int k = 0; k < 32; ++k) {             // c = cgrp*32 + k
    const unsigned idx = base + (unsigned)k * HW4_;
    f4v v = x4[idx];
    __builtin_nontemporal_store(v * g, &o4[idx]);
  }
}

extern "C" void kernel_launch(void* const* d_in, const int* in_sizes, int n_in,
                              void* d_out, int out_size, void* d_ws, size_t ws_size,
                              hipStream_t stream) {
  const float* x  = (const float*)d_in[0];   // [32,256,56,56]
  const float* wc = (const float*)d_in[1];   // [1,2,7,7]
  float* out = (float*)d_out;
  float* pool = (float*)d_ws;                // [B,2,HW] = 802,816 B

  sa_fused_kernel<<<GRID_, 256, 0, stream>>>(x, wc, out, pool);
}

// Round 4
// 263.693 us; speedup vs baseline: 1.2088x; 1.2088x over previous
//
#include <hip/hip_runtime.h>
#include <math.h>

// Problem constants (x: [32, 256, 56, 56] fp32)
#define B_    32
#define C_    256
#define H_    56
#define W_    56
#define HW_   (H_ * W_)        // 3136
#define BHW_  (B_ * HW_)       // 100352
#define HW4_  (HW_ / 4)        // 784 float4 per (b,c) plane
#define NF4_  (BHW_ / 4)       // 25088 global float4 positions
#define GRID_ 784              // 784 = 8 XCDs * 98 blocks
#define CHUNKF4_ 32            // 32 consecutive float4 per block
#define POSPB_   128           // 128 float positions per block
#define NXCD_ 8
#define F4PX_ (NF4_ / NXCD_)   // 3136 f4 per XCD slab = 4 whole images
#define JMAX_ ((GRID_ / NXCD_) - 1)  // 97

typedef float f4v __attribute__((ext_vector_type(4)));

// ---------------------------------------------------------------------------
// R3 post-mortem: global grid barrier cost ~116 us (fused 201 us vs ~85 us of
// phase work; FETCH+WRITE already optimal at 206 MB, VALUBusy 1.6% -> pure
// stall). The conv needs only a +/-3-row halo of pool = same-slab chunk
// neighbors j-2..j+2 (slabs are 4 whole images; deps clip at image edges).
// So: per-block monotonic epoch flags instead of a global barrier.
//   - g_flag[b] lives in zero-init device globals (not poisoned by harness),
//     incremented exactly once per replay -> epoch = replay count; no reset
//     needed across hipGraph replays.
//   - Each block waits for <=4 neighbors dispatched ~simultaneously on the
//     same XCD: no global straggler, no 784-deep atomic hotspot.
//   - Deadlock-free: VGPR<=128 (launch_bounds(256,4)) + LDS 9.75 KB -> 4
//     blocks/CU -> capacity 1024 >= 784, all blocks co-resident; spin is
//     bounded so a wrong assumption fails fast, never hangs.
// Also: phase 1/2b load batching 16/8-deep (R3 VGPR=36 -> only ~4 loads in
// flight; budget is 128) to raise memory-level parallelism.
// ---------------------------------------------------------------------------
__device__ unsigned g_flag[GRID_];   // zero-init, monotonic epochs

__global__ __launch_bounds__(256, 4) void sa_fused_kernel(
    const float* __restrict__ x, const float* __restrict__ wt,
    float* __restrict__ out, float* __restrict__ pool) {
  const int t = threadIdx.x;
  const unsigned b = blockIdx.x;
  const unsigned xcd = b % NXCD_;            // XCD-contiguous remap
  const unsigned j = b / NXCD_;              // 0..97 within slab
  const unsigned if4base = xcd * F4PX_ + j * CHUNKF4_;

  const int lane = t & 31;
  const int cgrp = t >> 5;                   // 0..7 (32 channels each)
  const unsigned if4 = if4base + (unsigned)lane;
  const unsigned bimg = if4 / HW4_;          // per-lane: handles image straddle
  const unsigned hw4 = if4 % HW4_;
  const f4v* __restrict__ x4 = (const f4v*)x;
  f4v* __restrict__ o4 = (f4v*)out;
  const unsigned base = (bimg * C_ + (unsigned)cgrp * 32u) * HW4_ + hw4;

  // ---- Phase 1: channel mean+max, 32 channels/thread, 16-deep load ILP ----
  f4v s = {0.f, 0.f, 0.f, 0.f};
  f4v m = {-INFINITY, -INFINITY, -INFINITY, -INFINITY};
#pragma unroll
  for (int kk = 0; kk < 32; kk += 16) {
    f4v v[16];
#pragma unroll
    for (int u = 0; u < 16; ++u)
      v[u] = x4[base + (unsigned)(kk + u) * HW4_];
#pragma unroll
    for (int u = 0; u < 16; ++u) {
      s += v[u];
      m = (f4v){fmaxf(m.x, v[u].x), fmaxf(m.y, v[u].y),
                fmaxf(m.z, v[u].z), fmaxf(m.w, v[u].w)};
    }
  }

  __shared__ f4v ssum[8][32];
  __shared__ f4v smax[8][32];
  ssum[cgrp][lane] = s;
  smax[cgrp][lane] = m;
  __syncthreads();

  if (t < 32) {
    f4v S = ssum[0][t];
    f4v M = smax[0][t];
#pragma unroll
    for (int g = 1; g < 8; ++g) {
      f4v sg = ssum[g][t];
      f4v mg = smax[g][t];
      S += sg;
      M = (f4v){fmaxf(M.x, mg.x), fmaxf(M.y, mg.y),
                fmaxf(M.z, mg.z), fmaxf(M.w, mg.w)};
    }
    f4v* p4 = (f4v*)pool;
    const unsigned jf4 = if4base + (unsigned)t;
    const unsigned bb = jf4 / HW4_;
    const unsigned hh = jf4 % HW4_;
    p4[bb * 2 * HW4_ + hh]        = S * (1.0f / (float)C_);  // avg plane
    p4[bb * 2 * HW4_ + HW4_ + hh] = M;                       // max plane
  }

  // ---- publish + neighbor wait (replaces global barrier) ----
  __shared__ unsigned s_epoch;
  __syncthreads();   // drains this block's pool stores (vmcnt0 before barrier)
  if (t == 0) {
    __threadfence();                          // release: pool visible agent-wide
    s_epoch = atomicAdd(&g_flag[b], 1u) + 1u; // epoch for this replay
  }
  __syncthreads();
  {
    const unsigned ep = s_epoch;
    if (t < 4) {
      const int dj = (t < 2) ? ((int)t - 2) : ((int)t - 1);  // -2,-1,+1,+2
      const int jn = (int)j + dj;
      if (jn >= 0 && jn <= JMAX_) {
        const unsigned nb = xcd + (unsigned)(NXCD_ * jn);
        unsigned spins = 0;
        while (__hip_atomic_load(&g_flag[nb], __ATOMIC_ACQUIRE,
                                 __HIP_MEMORY_SCOPE_AGENT) < ep) {
          __builtin_amdgcn_s_sleep(2);
          if (++spins > 20000000u) break;     // bounded: fail fast, never hang
        }
        __threadfence();                      // acquire side (L1 invalidate)
      }
    }
  }
  __syncthreads();

  // ---- Phase 2a: 7x7 conv + sigmoid into LDS gate ----
  __shared__ float partial[256];
  __shared__ f4v sgate4[CHUNKF4_];           // 128 gate floats
  {
    const int pos = t >> 1;                  // 0..127
    const int ic = t & 1;
    const unsigned p = if4base * 4u + (unsigned)pos;
    const unsigned bimg_a = p / HW_;
    const unsigned hw = p % HW_;
    const int h = (int)(hw / W_);
    const int w = (int)(hw % W_);
    const float* pl = pool + ((long)bimg_a * 2 + ic) * HW_;
    const float* wr0 = wt + ic * 49;
    float acc = 0.f;
#pragma unroll
    for (int kh = 0; kh < 7; ++kh) {
      const int ih = h + kh - 3;
      if (ih < 0 || ih >= H_) continue;
      const float* row = pl + ih * W_;
      const float* wr = wr0 + kh * 7;
#pragma unroll
      for (int kw = 0; kw < 7; ++kw) {
        const int iw = w + kw - 3;
        if (iw < 0 || iw >= W_) continue;
        acc = fmaf(row[iw], wr[kw], acc);
      }
    }
    partial[t] = acc;
  }
  __syncthreads();
  if (t < POSPB_) {
    float a = partial[2 * t] + partial[2 * t + 1];
    ((float*)sgate4)[t] = 1.0f / (1.0f + __expf(-a));
  }
  __syncthreads();

  // ---- Phase 2b: out = x * gate, 32 channels/thread, 8-deep load ILP ----
  const f4v g = sgate4[lane];
#pragma unroll
  for (int kk = 0; kk < 32; kk += 8) {
    f4v v[8];
#pragma unroll
    for (int u = 0; u < 8; ++u)
      v[u] = x4[base + (unsigned)(kk + u) * HW4_];
#pragma unroll
    for (int u = 0; u < 8; ++u)
      __builtin_nontemporal_store(v[u] * g, &o4[base + (unsigned)(kk + u) * HW4_]);
  }
}

extern "C" void kernel_launch(void* const* d_in, const int* in_sizes, int n_in,
                              void* d_out, int out_size, void* d_ws, size_t ws_size,
                              hipStream_t stream) {
  const float* x  = (const float*)d_in[0];   // [32,256,56,56]
  const float* wc = (const float*)d_in[1];   // [1,2,7,7]
  float* out = (float*)d_out;
  float* pool = (float*)d_ws;                // [B,2,HW] = 802,816 B

  sa_fused_kernel<<<GRID_, 256, 0, stream>>>(x, wc, out, pool);
}

// Round 5
// 209.186 us; speedup vs baseline: 1.5238x; 1.2606x over previous
//
#include <hip/hip_runtime.h>
#include <math.h>

// Problem constants (x: [32, 256, 56, 56] fp32)
#define B_    32
#define C_    256
#define H_    56
#define W_    56
#define HW_   3136
#define HW4_  784               // float4 per channel plane
#define NF4_  (B_ * C_ * HW4_)  // 6,422,528 f4 total

typedef float f4v __attribute__((ext_vector_type(4)));

static __device__ __forceinline__ f4v f4max(f4v a, f4v b) {
  return (f4v){fmaxf(a.x, b.x), fmaxf(a.y, b.y), fmaxf(a.z, b.z), fmaxf(a.w, b.w)};
}

// ===========================================================================
// NEW PATH (R5): linear-streaming 3-kernel pipeline.
// R0..R4 evidence: every channel-strided variant runs 1.0-2.8 TB/s while
// fill/copy hit 6.3-6.9 TB/s -> DRAM page locality theory. All reads/writes
// here walk memory in >=1-KB-per-instruction contiguous runs.
// ===========================================================================

// ---------------------------------------------------------------------------
// K1: partial reduce. 1024 blocks = 32 images x 32 groups of 8 channel-planes.
// Block streams a contiguous 98-KB span of x. Wave w owns positions
// [196w, 196w+196); for each position it loads 8 planes (8 independent 1-KB
// contiguous wave-loads in flight), reduces in registers, writes partial
// sum/max planes to ws: part4[k*1568 + q] (sum), [+784] (max). Coalesced.
// ---------------------------------------------------------------------------
__global__ __launch_bounds__(256, 4) void k1_partial(
    const float* __restrict__ x, float* __restrict__ part) {
  const int t = threadIdx.x;
  const unsigned k = blockIdx.x;          // 0..1023
  const unsigned img = k >> 5;            // 0..31
  const unsigned grp = k & 31u;           // 0..31
  const f4v* __restrict__ x4 = (const f4v*)x;
  f4v* __restrict__ p4 = (f4v*)part;
  const unsigned xbase = (img * 256u + grp * 8u) * 784u;  // first plane, f4
  const int w = t >> 6;                   // wave 0..3
  const int l = t & 63;

#pragma unroll
  for (int it = 0; it < 4; ++it) {
    const int off = it * 64 + l;
    if (off < 196) {                      // it=3: only lanes 0..3
      const unsigned q = 196u * (unsigned)w + (unsigned)off;
      f4v v0 = x4[xbase + 0u * 784u + q];
      f4v v1 = x4[xbase + 1u * 784u + q];
      f4v v2 = x4[xbase + 2u * 784u + q];
      f4v v3 = x4[xbase + 3u * 784u + q];
      f4v v4 = x4[xbase + 4u * 784u + q];
      f4v v5 = x4[xbase + 5u * 784u + q];
      f4v v6 = x4[xbase + 6u * 784u + q];
      f4v v7 = x4[xbase + 7u * 784u + q];
      f4v s = ((v0 + v1) + (v2 + v3)) + ((v4 + v5) + (v6 + v7));
      f4v m = f4max(f4max(f4max(v0, v1), f4max(v2, v3)),
                    f4max(f4max(v4, v5), f4max(v6, v7)));
      p4[k * 1568u + q]        = s;
      p4[k * 1568u + 784u + q] = m;
    }
  }
}

// ---------------------------------------------------------------------------
// K1b: combine 32 partials/position + 7x7 conv + sigmoid -> gate planes.
// 224 blocks = 32 images x 7 row-tiles (8 rows each). Stage combined
// avg/max halo (14 rows x 56 = 196 f4 per plane) in LDS, then conv+sigmoid
// for 448 positions, scalar store to gate[img*3136 + r*56 + w].
// Partials are L2/L3-resident (just written). SAME padding -> OOB rows = 0.
// ---------------------------------------------------------------------------
__global__ __launch_bounds__(256) void k1b_combine_conv(
    const float* __restrict__ part, const float* __restrict__ wt,
    float* __restrict__ gate) {
  const int t = threadIdx.x;
  const unsigned blk = blockIdx.x;        // 0..223
  const unsigned img = blk / 7u;
  const int r0 = (int)(blk % 7u) * 8;     // tile rows r0..r0+7

  __shared__ float lsum[784];             // 14 rows x 56 (avg, pre-scaled)
  __shared__ float lmax[784];
  const f4v* __restrict__ p4 = (const f4v*)part;

  // stage combined halo: 392 f4-slots (196 sum + 196 max)
  for (int s = t; s < 392; s += 256) {
    const int is_max = (s >= 196);
    const int sl = is_max ? (s - 196) : s;   // 0..195
    const int lr = sl / 14;                  // local row 0..13
    const int c  = sl % 14;                  // f4 col
    const int row = r0 - 3 + lr;
    f4v acc;
    if (row < 0 || row >= 56) {
      acc = (f4v){0.f, 0.f, 0.f, 0.f};       // SAME padding = 0
    } else {
      const unsigned qq = (unsigned)(row * 14 + c);
      if (!is_max) {
        f4v a = {0.f, 0.f, 0.f, 0.f};
#pragma unroll 8
        for (int g = 0; g < 32; ++g)
          a += p4[(img * 32u + (unsigned)g) * 1568u + qq];
        acc = a * (1.0f / 256.0f);           // fold mean scale here
      } else {
        f4v a = {-INFINITY, -INFINITY, -INFINITY, -INFINITY};
#pragma unroll 8
        for (int g = 0; g < 32; ++g)
          a = f4max(a, p4[(img * 32u + (unsigned)g) * 1568u + 784u + qq]);
        acc = a;
      }
    }
    ((f4v*)(is_max ? lmax : lsum))[sl] = acc;
  }
  __syncthreads();

  // conv + sigmoid: 448 positions, up to 2 per thread
  const float* __restrict__ w0 = wt;       // avg-channel taps
  const float* __restrict__ w1 = wt + 49;  // max-channel taps
#pragma unroll
  for (int pp = 0; pp < 2; ++pp) {
    const int pos = t + 256 * pp;
    if (pos < 448) {
      const int lro = pos / 56;            // 0..7 within tile
      const int wc = pos % 56;
      float a = 0.f;
#pragma unroll
      for (int kh = 0; kh < 7; ++kh) {
        const float* rs = lsum + (lro + kh) * 56;
        const float* rm = lmax + (lro + kh) * 56;
        const float* t0 = w0 + kh * 7;
        const float* t1 = w1 + kh * 7;
#pragma unroll
        for (int kw = 0; kw < 7; ++kw) {
          const int iw = wc + kw - 3;
          if (iw >= 0 && iw < 56) {
            a = fmaf(rs[iw], t0[kw], a);
            a = fmaf(rm[iw], t1[kw], a);
          }
        }
      }
      gate[img * 3136u + (unsigned)(r0 + lro) * 56u + (unsigned)wc] =
          1.0f / (1.0f + __expf(-a));
    }
  }
}

// ---------------------------------------------------------------------------
// K2: apply. 1568 blocks x 256 thr; block owns 4096 CONSECUTIVE f4 (64 KB)
// of x/out -> pure linear streaming, 1 KB/wave-instruction, never straddles
// an image (4096*49 = 200704 = one image). Gate plane (784 f4 = 12.5 KB)
// staged in LDS; per-iteration gate index = (S + t + 256*it) mod 784.
// x is L3-resident from K1; NT stores keep out from evicting it.
// ---------------------------------------------------------------------------
__global__ __launch_bounds__(256) void k2_apply(
    const float* __restrict__ x, const float* __restrict__ gate,
    float* __restrict__ out) {
  const int t = threadIdx.x;
  const unsigned k = blockIdx.x;          // 0..1567
  const unsigned img = k / 49u;
  const unsigned S = (176u * (k % 49u)) % 784u;  // 4096 mod 784 = 176

  __shared__ f4v lg[784];
  const f4v* __restrict__ g4 = (const f4v*)gate;
#pragma unroll
  for (int it = 0; it < 4; ++it) {
    const int idx = t + 256 * it;
    if (idx < 784) lg[idx] = g4[img * 784u + (unsigned)idx];
  }
  __syncthreads();

  const f4v* __restrict__ x4 = (const f4v*)x;
  f4v* __restrict__ o4 = (f4v*)out;
  const unsigned base = k * 4096u + (unsigned)t;
  unsigned qc = S + (unsigned)t;
  if (qc >= 784u) qc -= 784u;

#pragma unroll
  for (int hb = 0; hb < 2; ++hb) {
    f4v v[8];
#pragma unroll
    for (int u = 0; u < 8; ++u)          // 8 linear 1-KB loads in flight
      v[u] = x4[base + (unsigned)(hb * 8 + u) * 256u];
#pragma unroll
    for (int u = 0; u < 8; ++u) {
      const f4v g = lg[qc];
      __builtin_nontemporal_store(v[u] * g,
                                  &o4[base + (unsigned)(hb * 8 + u) * 256u]);
      qc += 256u;
      if (qc >= 784u) qc -= 784u;
    }
  }
}

// ===========================================================================
// FALLBACK PATH: R0's proven two-kernel config (202.25 us) — used only if
// ws_size < 26.1 MB needed by the new path. Host-side branch (graph-safe).
// ===========================================================================
__global__ __launch_bounds__(256) void sa_reduce_kernel(
    const float* __restrict__ x, float* __restrict__ pool) {
  const int t = threadIdx.x;
  const int lane = t & 15;
  const int cgrp = t >> 4;
  const unsigned if4 = (unsigned)blockIdx.x * 16u + (unsigned)lane;
  const unsigned bimg = if4 / 784u;
  const unsigned hw4 = if4 % 784u;
  const f4v* __restrict__ x4 = (const f4v*)x;
  const unsigned base = (bimg * 256u + (unsigned)cgrp) * 784u + hw4;

  f4v s = {0.f, 0.f, 0.f, 0.f};
  f4v m = {-INFINITY, -INFINITY, -INFINITY, -INFINITY};
#pragma unroll 8
  for (int kk = 0; kk < 16; ++kk) {
    f4v v = x4[base + (unsigned)(kk * 16) * 784u];
    s += v;
    m = f4max(m, v);
  }
  __shared__ f4v ssum[16][16];
  __shared__ f4v smax[16][16];
  ssum[cgrp][lane] = s;
  smax[cgrp][lane] = m;
  __syncthreads();
  if (t < 16) {
    f4v S = ssum[0][t];
    f4v M = smax[0][t];
#pragma unroll
    for (int g = 1; g < 16; ++g) {
      S += ssum[g][t];
      M = f4max(M, smax[g][t]);
    }
    f4v* p4 = (f4v*)pool;
    const unsigned jf4 = (unsigned)blockIdx.x * 16u + (unsigned)t;
    const unsigned bb = jf4 / 784u;
    const unsigned hh = jf4 % 784u;
    p4[bb * 1568u + hh]        = S * (1.0f / 256.0f);
    p4[bb * 1568u + 784u + hh] = M;
  }
}

__global__ __launch_bounds__(256) void sa_conv_apply_kernel(
    const float* __restrict__ x, const float* __restrict__ pool,
    const float* __restrict__ wt, float* __restrict__ out) {
  const int t = threadIdx.x;
  __shared__ float partial[128];
  __shared__ f4v sgate4[16];
  if (t < 128) {
    const int pos = t >> 1;
    const int ic = t & 1;
    const unsigned p = (unsigned)blockIdx.x * 64u + (unsigned)pos;
    const unsigned bimg = p / 3136u;
    const unsigned hw = p % 3136u;
    const int h = (int)(hw / 56u);
    const int w = (int)(hw % 56u);
    const float* pl = pool + ((long)bimg * 2 + ic) * 3136;
    const float* wr0 = wt + ic * 49;
    float acc = 0.f;
#pragma unroll
    for (int kh = 0; kh < 7; ++kh) {
      const int ih = h + kh - 3;
      if (ih < 0 || ih >= 56) continue;
      const float* row = pl + ih * 56;
      const float* wr = wr0 + kh * 7;
#pragma unroll
      for (int kw = 0; kw < 7; ++kw) {
        const int iw = w + kw - 3;
        if (iw < 0 || iw >= 56) continue;
        acc = fmaf(row[iw], wr[kw], acc);
      }
    }
    partial[t] = acc;
  }
  __syncthreads();
  if (t < 64) {
    float a = partial[2 * t] + partial[2 * t + 1];
    ((float*)sgate4)[t] = 1.0f / (1.0f + __expf(-a));
  }
  __syncthreads();

  const int lane = t & 15;
  const int cgrp = t >> 4;
  const unsigned if4 = (unsigned)blockIdx.x * 16u + (unsigned)lane;
  const unsigned bimg = if4 / 784u;
  const unsigned hw4 = if4 % 784u;
  const unsigned base = (bimg * 256u + (unsigned)cgrp) * 784u + hw4;
  const f4v* __restrict__ x4 = (const f4v*)x;
  f4v* __restrict__ o4 = (f4v*)out;
  const f4v g = sgate4[lane];
#pragma unroll 8
  for (int kk = 0; kk < 16; ++kk) {
    const unsigned idx = base + (unsigned)(kk * 16) * 784u;
    f4v v = x4[idx];
    __builtin_nontemporal_store(v * g, &o4[idx]);
  }
}

// ===========================================================================
extern "C" void kernel_launch(void* const* d_in, const int* in_sizes, int n_in,
                              void* d_out, int out_size, void* d_ws, size_t ws_size,
                              hipStream_t stream) {
  const float* x  = (const float*)d_in[0];   // [32,256,56,56]
  const float* wc = (const float*)d_in[1];   // [1,2,7,7]
  float* out = (float*)d_out;

  // new path needs: partials 1024*1568 f4 + gate 32*784 f4 = 26.1 MB
  const size_t PART_F4 = 1024u * 1568u;            // 1,605,632 f4
  const size_t GATE_F4 = 32u * 784u;               // 25,088 f4
  const size_t NEED = (PART_F4 + GATE_F4) * 16u;   // bytes

  if (ws_size >= NEED) {
    float* part = (float*)d_ws;
    float* gate = (float*)d_ws + PART_F4 * 4;      // float offset
    k1_partial<<<1024, 256, 0, stream>>>(x, part);
    k1b_combine_conv<<<224, 256, 0, stream>>>(part, wc, gate);
    k2_apply<<<1568, 256, 0, stream>>>(x, gate, out);
  } else {
    float* pool = (float*)d_ws;                    // [B,2,HW] = 802,816 B
    sa_reduce_kernel<<<1568, 256, 0, stream>>>(x, pool);
    sa_conv_apply_kernel<<<1568, 256, 0, stream>>>(x, pool, wc, out);
  }
}

// Round 6
// 203.398 us; speedup vs baseline: 1.5672x; 1.0285x over previous
//
#include <hip/hip_runtime.h>
#include <math.h>

// Problem constants (x: [32, 256, 56, 56] fp32)
#define B_    32
#define C_    256
#define H_    56
#define W_    56
#define HW_   3136
#define HW4_  784               // float4 per channel plane
#define NF4_  25088             // B_*HW4_ f4 gate positions

typedef float f4v __attribute__((ext_vector_type(4)));

static __device__ __forceinline__ f4v f4max(f4v a, f4v b) {
  return (f4v){fmaxf(a.x, b.x), fmaxf(a.y, b.y), fmaxf(a.z, b.z), fmaxf(a.w, b.w)};
}

// ---------------------------------------------------------------------------
// K1 (R6): channel reduce with 1-KB contiguous wave segments.
// A/B vs R0's K1 (4 x 256-B scattered segments/wave-load): ONLY K1 changes
// this round; K2 is byte-identical to R0's proven sa_conv_apply_kernel.
// 392 blocks x 512 threads (8 waves). Block owns 64 consecutive f4 gate
// positions; lane = t&63 = f4 position -> each wave-load of channel c is
// 64 lanes x 16 B CONSECUTIVE = one 1-KB segment (the m13-copy shape that
// hits 6.29 TB/s). Wave w sweeps channels w+8k (k=0..31), unroll-8 -> 8
// independent 1-KB loads in flight per wave. Per-lane bimg/hw4 handles the
// ~32 image-straddling blocks (wave then issues 2 segments - fine).
// Cross-wave combine via 16 KB LDS; pool written in R0's [B,2,HW] layout.
// Known cost: 392 blocks = 1.53/CU -> 2-round makespan (~+5 us tail).
// ---------------------------------------------------------------------------
__global__ __launch_bounds__(512) void k1_reduce_linear(
    const float* __restrict__ x, float* __restrict__ pool) {
  const int t = threadIdx.x;
  const int lane = t & 63;
  const int w = t >> 6;                       // wave 0..7
  const unsigned if4 = (unsigned)blockIdx.x * 64u + (unsigned)lane;  // < 25088
  const unsigned bimg = if4 / 784u;
  const unsigned hw4 = if4 % 784u;
  const f4v* __restrict__ x4 = (const f4v*)x;
  const unsigned base0 = bimg * (256u * 784u) + hw4;

  f4v s = {0.f, 0.f, 0.f, 0.f};
  f4v m = {-INFINITY, -INFINITY, -INFINITY, -INFINITY};
#pragma unroll 8
  for (int k = 0; k < 32; ++k) {              // c = w + 8k
    const unsigned c = (unsigned)w + 8u * (unsigned)k;
    f4v v = x4[base0 + c * 784u];
    s += v;
    m = f4max(m, v);
  }

  __shared__ f4v ssum[8][64];                 // 8 KB
  __shared__ f4v smax[8][64];                 // 8 KB
  ssum[w][lane] = s;
  smax[w][lane] = m;
  __syncthreads();

  if (t < 64) {
    f4v S = ssum[0][t];
    f4v M = smax[0][t];
#pragma unroll
    for (int g = 1; g < 8; ++g) {
      S += ssum[g][t];
      M = f4max(M, smax[g][t]);
    }
    f4v* p4 = (f4v*)pool;
    const unsigned jf4 = (unsigned)blockIdx.x * 64u + (unsigned)t;
    const unsigned bb = jf4 / 784u;
    const unsigned hh = jf4 % 784u;
    p4[bb * 1568u + hh]        = S * (1.0f / 256.0f);  // avg plane
    p4[bb * 1568u + 784u + hh] = M;                    // max plane
  }
}

// ---------------------------------------------------------------------------
// K2: byte-identical to R0's sa_conv_apply_kernel (202.25 us config).
// 1568 blocks x 256 threads; 64 gate positions/block; conv from pool
// (L2/L3-resident) -> sigmoid in LDS -> apply to 256 channels, NT stores.
// ---------------------------------------------------------------------------
__global__ __launch_bounds__(256) void sa_conv_apply_kernel(
    const float* __restrict__ x, const float* __restrict__ pool,
    const float* __restrict__ wt, float* __restrict__ out) {
  const int t = threadIdx.x;
  __shared__ float partial[128];
  __shared__ f4v sgate4[16];
  if (t < 128) {
    const int pos = t >> 1;
    const int ic = t & 1;
    const unsigned p = (unsigned)blockIdx.x * 64u + (unsigned)pos;
    const unsigned bimg = p / 3136u;
    const unsigned hw = p % 3136u;
    const int h = (int)(hw / 56u);
    const int w = (int)(hw % 56u);
    const float* pl = pool + ((long)bimg * 2 + ic) * 3136;
    const float* wr0 = wt + ic * 49;
    float acc = 0.f;
#pragma unroll
    for (int kh = 0; kh < 7; ++kh) {
      const int ih = h + kh - 3;
      if (ih < 0 || ih >= 56) continue;
      const float* row = pl + ih * 56;
      const float* wr = wr0 + kh * 7;
#pragma unroll
      for (int kw = 0; kw < 7; ++kw) {
        const int iw = w + kw - 3;
        if (iw < 0 || iw >= 56) continue;
        acc = fmaf(row[iw], wr[kw], acc);
      }
    }
    partial[t] = acc;
  }
  __syncthreads();
  if (t < 64) {
    float a = partial[2 * t] + partial[2 * t + 1];
    ((float*)sgate4)[t] = 1.0f / (1.0f + __expf(-a));
  }
  __syncthreads();

  const int lane = t & 15;
  const int cgrp = t >> 4;
  const unsigned if4 = (unsigned)blockIdx.x * 16u + (unsigned)lane;
  const unsigned bimg = if4 / 784u;
  const unsigned hw4 = if4 % 784u;
  const unsigned base = (bimg * 256u + (unsigned)cgrp) * 784u + hw4;
  const f4v* __restrict__ x4 = (const f4v*)x;
  f4v* __restrict__ o4 = (f4v*)out;
  const f4v g = sgate4[lane];
#pragma unroll 8
  for (int kk = 0; kk < 16; ++kk) {
    const unsigned idx = base + (unsigned)(kk * 16) * 784u;
    f4v v = x4[idx];
    __builtin_nontemporal_store(v * g, &o4[idx]);
  }
}

extern "C" void kernel_launch(void* const* d_in, const int* in_sizes, int n_in,
                              void* d_out, int out_size, void* d_ws, size_t ws_size,
                              hipStream_t stream) {
  const float* x  = (const float*)d_in[0];   // [32,256,56,56]
  const float* wc = (const float*)d_in[1];   // [1,2,7,7]
  float* out = (float*)d_out;
  float* pool = (float*)d_ws;                // [B,2,HW] = 802,816 B

  k1_reduce_linear<<<392, 512, 0, stream>>>(x, pool);
  sa_conv_apply_kernel<<<1568, 256, 0, stream>>>(x, pool, wc, out);
}